// Round 8
// baseline (324.246 us; speedup 1.0000x reference)
//
#include <hip/hip_runtime.h>
#include <hip/hip_bf16.h>

// AGATCellWithMLP: B=8,N=2048,D=64,Q=16,H=2,C=129,C8=16,K=8192.
// Round 21: r20 + prefetch-placement fix. r19/r20 issued kpre/mpre (next
// tile's K frags + mask) immediately BEFORE __syncthreads; the compiler's
// vmcnt(0)-before-s_barrier drained those fresh loads every tile (~300cy
// stall/tile, the exact stall the prefetch was meant to hide). Now issued
// AFTER the barrier (with the DMA): they fly across PV, are consumed at the
// next QK, and are never outstanding at a barrier. Everything else = r20
// (column-split 2 blocks/CU, atomic-free, dbuf gll, XOR involution, setprio).

typedef _Float16 h2_t __attribute__((ext_vector_type(2)));
typedef _Float16 h8_t __attribute__((ext_vector_type(8)));
typedef float    f4_t __attribute__((ext_vector_type(4)));
#define MFMA16x32(a,b,c) __builtin_amdgcn_mfma_f32_16x16x32_f16(a,b,c,0,0,0)

// ---- workspace layout (byte offsets; total 17,536,000 <= proven 22,025,248) --
#define OB_QG    0          // fp16 [2][8192][16]   524288
#define OB_KG    524288     // fp16 [2][8192][16]   524288
#define OB_VT    1048576    // fp16 [2][144][8192]  4718592
#define OB_MASK  5767168    // u32  [4][2048][64]   2097152
#define OB_WALL  7864320    // fp16 swz             107520
#define OB_HACC  7971840    // f32  [2][8192][132]  8650752 (+ lsum contiguous)
#define OB_LSUM  16622592   // f32  [2][8192]       65536
#define OB_WTRU  16688128   // fp16 swz [69][8][64][8]  565248
#define OB_WTC   17253376   // fp16 swz [69][4][64][8]  282624

// ---------------- pack_adj: first 4 batches of adj -> bitmask ----------------
__global__ __launch_bounds__(256) void pack_adj(const int* __restrict__ adj,
                                                unsigned* __restrict__ mask) {
    long tg = (long)blockIdx.x * 256 + threadIdx.x;
    for (int it = 0; it < 32; ++it) {
        long i = tg + (long)it * 524288;
        int a = adj[i];
        unsigned long long bal = __ballot(a != 0);
        if ((threadIdx.x & 63) == 0)
            *(unsigned long long*)(mask + (i >> 5)) = bal;
    }
}

// ---------------- repack_all: Wall + WtRu + WtC (swizzled) -------------------
__global__ __launch_bounds__(256) void repack_all(
    const float* __restrict__ Wq, const float* __restrict__ bq,
    const float* __restrict__ Wk, const float* __restrict__ bk,
    const float* __restrict__ Wv, const float* __restrict__ bv,
    const float* __restrict__ Wr, const float* __restrict__ br,
    const float* __restrict__ Wu, const float* __restrict__ bu,
    const float* __restrict__ Wc, const float* __restrict__ bc,
    _Float16* __restrict__ Wall, _Float16* __restrict__ WtRu,
    _Float16* __restrict__ WtC) {
    int idx = blockIdx.x * 256 + threadIdx.x;   // 6720 + 35328 + 17664 = 59712
    if (idx < 6720) {
        int ct = idx / 320;
        int rem = idx % 320;
        int s = rem >> 6, lane = rem & 63;
        int n = ct * 16 + (lane & 15);
        int quad = lane >> 4;
        int h2 = (n >= 164) ? 1 : 0;
        int nn = n - h2 * 164;
        h8_t v;
        #pragma unroll
        for (int j = 0; j < 8; ++j) {
            int k = s * 32 + quad * 8 + j;
            float f = 0.f;
            if (n < 328) {
                if (nn < 16) {
                    if (k < 129)       f = Wq[(h2 * 129 + k) * 16 + nn];
                    else if (k == 129) f = bq[h2 * 16 + nn];
                } else if (nn < 32) {
                    int d = nn - 16;
                    if (k < 129)       f = Wk[(h2 * 129 + k) * 16 + d];
                    else if (k == 129) f = bk[h2 * 16 + d];
                } else {
                    int vc = nn - 32;
                    if (vc < 129) {
                        if (k < 129)       f = Wv[(h2 * 129 + k) * 129 + vc];
                        else if (k == 129) f = bv[h2 * 129 + vc];
                    }
                }
            }
            v[j] = (_Float16)f;
        }
        *(h8_t*)(Wall + (size_t)idx * 8) = v;
    } else if (idx < 6720 + 35328) {
        int i2 = idx - 6720;
        int s = i2 / 512;
        int rem = i2 % 512;
        int ct = rem >> 6, lane = rem & 63;
        int o = ct * 16 + (lane & 15);
        int quad = lane >> 4;
        const float* W = (o < 64) ? Wr : Wu;
        const float* bb = (o < 64) ? br : bu;
        int oc = o & 63;
        h8_t v;
        #pragma unroll
        for (int j = 0; j < 8; ++j) {
            int kk = s * 32 + quad * 8 + j;
            float f = 0.f;
            if (kk < 2176) {
                int q = kk / 136, c = kk % 136;
                if (c < 129) f = W[(q * 129 + c) * 64 + oc];
            } else if (kk < 2192) {
                f = bb[(kk - 2176) * 64 + oc];
            }
            v[j] = (_Float16)f;
        }
        *(h8_t*)(WtRu + (size_t)i2 * 8) = v;
    } else if (idx < 59712) {
        int i2 = idx - 6720 - 35328;
        int s = i2 / 256;
        int rem = i2 % 256;
        int ct = rem >> 6, lane = rem & 63;
        int o = ct * 16 + (lane & 15);
        int quad = lane >> 4;
        h8_t v;
        #pragma unroll
        for (int j = 0; j < 8; ++j) {
            int kk = s * 32 + quad * 8 + j;
            float f = 0.f;
            if (kk < 2176) {
                int q = kk / 136, c = kk % 136;
                if (c < 129) f = Wc[(q * 129 + c) * 64 + o];
            } else if (kk < 2192) {
                f = bc[(kk - 2176) * 64 + o];
            }
            v[j] = (_Float16)f;
        }
        *(h8_t*)(WtC + (size_t)i2 * 8) = v;
    }
}

// ---------------- qkv via MFMA; v staged in LDS -> coalesced vT stores -------
__global__ __launch_bounds__(256) void qkv_mfma(
    const float* __restrict__ x, const float* __restrict__ h,
    const _Float16* __restrict__ Wall,
    _Float16* __restrict__ qg, _Float16* __restrict__ kg,
    _Float16* __restrict__ vT) {
    __shared__ _Float16 at[16 * 168];
    __shared__ _Float16 vls[264 * 16];   // [vcol][row] fp16
    int t = threadIdx.x;
    int row0 = blockIdx.x * 16;
    for (int idx = t; idx < 16 * 160; idx += 256) {
        int r = idx / 160, c = idx % 160;
        int grow = row0 + r;
        float v = 0.f;
        if (c < 65)       v = x[grow * 65 + c];
        else if (c < 129) v = h[grow * 64 + (c - 65)];
        else if (c == 129) v = 1.0f;
        at[r * 168 + c] = (_Float16)v;
    }
    __syncthreads();
    int lane = t & 63, w = t >> 6;
    int l16 = lane & 15, quad = lane >> 4;
    for (int ct = w; ct < 21; ct += 4) {
        f4_t acc; acc[0]=0.f; acc[1]=0.f; acc[2]=0.f; acc[3]=0.f;
        int n = ct * 16 + l16;
        const _Float16* wp = Wall + ((size_t)ct * 320 + lane) * 8;
        #pragma unroll
        for (int s = 0; s < 5; ++s) {
            h8_t a = *(const h8_t*)(at + l16 * 168 + s * 32 + quad * 8);
            h8_t b = *(const h8_t*)(wp + (size_t)s * 512);
            acc = MFMA16x32(a, b, acc);
        }
        if (n < 328) {
            int h2 = (n >= 164) ? 1 : 0;
            int nn = n - h2 * 164;
            #pragma unroll
            for (int r = 0; r < 4; ++r) {
                int row = quad * 4 + r;
                _Float16 v = (_Float16)acc[r];
                if (nn < 16)      qg[(h2 * 8192 + row0 + row) * 16 + nn] = v;
                else if (nn < 32) kg[(h2 * 8192 + row0 + row) * 16 + (nn - 16)] = v;
                else              vls[(h2 * 132 + (nn - 32)) * 16 + row] = v;
            }
        }
    }
    __syncthreads();
    // flush v: 264 cols x 16 rows as 2 x 16B bursts per col
    for (int idx = t; idx < 528; idx += 256) {
        int col = idx >> 1, half = idx & 1;
        int h2 = (col >= 132) ? 1 : 0;
        int cc = col - h2 * 132;
        uint4 v = ((const uint4*)vls)[idx];
        *(uint4*)(vT + ((size_t)(h2 * 144 + cc)) * 8192 + row0 + half * 8) = v;
    }
}

// --- attention: column-split, atomic-free, post-barrier prefetch (r21) -------
__global__ __launch_bounds__(256) void attn_fused(
    const _Float16* __restrict__ qg, const _Float16* __restrict__ kg,
    const _Float16* __restrict__ vT, const unsigned* __restrict__ mask,
    float* __restrict__ hacc, float* __restrict__ lsum, int ntiles) {
    __shared__ _Float16 vsm[2 * 5120];   // dbuf; up to 10 chunks x 1KB per buf
    __shared__ _Float16 pT[4 * 16 * 88];
    int t = threadIdx.x;
    // 512 blocks: pid&7 = XCD = hb (slice L2-resident); j = pid>>3:
    // nt = j&31 (q-tile), cs = j>>5 (column split half).
    int pid = blockIdx.x + 64 * blockIdx.y;
    int hb = pid & 7, j = pid >> 3;
    int nt = j & 31, cs = j >> 5;
    int h2 = hb >> 2, b = hb & 3;
    int base = h2 * 8192 + b * 2048;
    int n0 = nt * 64;
    int nbase = cs ? 5 : 0;              // first nb owned by this block
    int jj0 = cs ? 10 : 0, jjN = cs ? 18 : 10;   // staged V chunk range
    int lane = t & 63, w = t >> 6;
    int l16 = lane & 15, q = lane >> 4;
    int qrow = n0 + w * 16 + l16;
    _Float16* pTw = pT + w * 16 * 88;
    h8_t zero8;
    #pragma unroll
    for (int i = 0; i < 8; ++i) zero8[i] = (_Float16)0.f;
    h8_t qf = zero8;
    if (q < 2) qf = *(const h8_t*)(qg + (base + qrow) * 16 + 8 * q);
    const unsigned* mrw = mask + (b * 2048 + qrow) * 64;
    f4_t acc[5];
    #pragma unroll
    for (int i = 0; i < 5; ++i) { acc[i][0]=0.f; acc[i][1]=0.f; acc[i][2]=0.f; acc[i][3]=0.f; }
    float l_run = 0.f;

    // gll staging: LOCAL chunk s = jj-jj0 covers local rows 8s..8s+7. Lane L
    // writes slot byte s*1024+16L; stored key-chunk (L&7)^(L>>3) = involution
    // with read-side XOR on (local_row&7). cs offsets are multiples of 8 so
    // the involution is unchanged.
    int vcol_l = (lane >> 3);
    int kch_l  = (lane & 7) ^ vcol_l;
    const _Float16* vtb = vT + (size_t)h2 * 144 * 8192 + b * 2048 + 8 * kch_l;

    h8_t kpre[4];
    uint2 mpre;
    // prologue: DMA tile 0 -> buf 0; K/mask prefetch tile 0
    for (int jj = jj0 + w; jj < jjN; jj += 4)
        __builtin_amdgcn_global_load_lds(
            (const void*)(vtb + (size_t)(8 * jj + vcol_l) * 8192),
            (void*)(vsm + (jj - jj0) * 512), 16, 0, 0);
    #pragma unroll
    for (int ct = 0; ct < 4; ++ct) {
        kpre[ct] = zero8;
        if (q < 2)
            kpre[ct] = *(const h8_t*)(kg + (base + 16 * ct + l16) * 16 + 8 * q);
    }
    mpre = *(const uint2*)mrw;

    for (int mt = 0; mt < ntiles; ++mt) {
        int cur = mt & 1;
        // ---- QK + softmax (V DMA(mt) into buf cur in flight underneath) ----
        h8_t kf[4];
        #pragma unroll
        for (int ct = 0; ct < 4; ++ct) kf[ct] = kpre[ct];
        uint2 mw = mpre;
        f4_t st[4];
        #pragma unroll
        for (int ct = 0; ct < 4; ++ct) {
            f4_t z4; z4[0]=0.f; z4[1]=0.f; z4[2]=0.f; z4[3]=0.f;
            st[ct] = MFMA16x32(kf[ct], qf, z4);
        }
        #pragma unroll
        for (int ct = 0; ct < 4; ++ct) {
            unsigned wb = (ct < 2) ? mw.x : mw.y;
            float p[4];
            #pragma unroll
            for (int r = 0; r < 4; ++r) {
                float sc = st[ct][r] * 0.25f;
                sc = sc > 0.f ? sc : 0.2f * sc;
                int bit = ((ct & 1) ? 16 : 0) + 4 * q + r;
                p[r] = ((wb >> bit) & 1u) ? __expf(sc) : 0.f;
                l_run += p[r];
            }
            h2_t p01; p01[0] = (_Float16)p[0]; p01[1] = (_Float16)p[1];
            h2_t p23; p23[0] = (_Float16)p[2]; p23[1] = (_Float16)p[3];
            *(h2_t*)(pTw + l16 * 88 + 16 * ct + 4 * q)     = p01;
            *(h2_t*)(pTw + l16 * 88 + 16 * ct + 4 * q + 2) = p23;
        }
        // ONE barrier: per-wave vmcnt(0) drain completes DMA(mt) (issued a
        // full phase ago); all waves done with PV(mt-1) on buf cur^1. No
        // fresh loads are outstanding here (kpre/mpre issue moved below).
        __syncthreads();
        if (mt + 1 < ntiles) {
            int m1 = (mt + 1) * 64;
            // DMA next tile's V into the buffer PV(mt-1) just released
            for (int jj = jj0 + w; jj < jjN; jj += 4)
                __builtin_amdgcn_global_load_lds(
                    (const void*)(vtb + (size_t)(8 * jj + vcol_l) * 8192 + m1),
                    (void*)(vsm + (cur ^ 1) * 5120 + (jj - jj0) * 512), 16, 0, 0);
            // K/mask prefetch issued POST-barrier: lands during PV(mt),
            // consumed at QK(mt+1), never drained by a barrier.
            #pragma unroll
            for (int ct = 0; ct < 4; ++ct) {
                kpre[ct] = zero8;
                if (q < 2)
                    kpre[ct] = *(const h8_t*)(kg + (base + m1 + 16 * ct + l16) * 16 + 8 * q);
            }
            mpre = *(const uint2*)(mrw + (m1 >> 5));
        }
        // ---- PV on buf cur (swizzled reads; local rows 16i+l16) ----
        // cs=1 runs a 5th dummy nb into unwritten LDS; its store is guarded.
        const char* vbb = (const char*)(vsm + cur * 5120);
        __builtin_amdgcn_s_setprio(1);
        #pragma unroll
        for (int kh = 0; kh < 2; ++kh) {
            h8_t ap = *(const h8_t*)(pTw + l16 * 88 + 32 * kh + 8 * q);
            int xsw = (((kh << 2) + q) ^ (l16 & 7)) << 4;
            #pragma unroll
            for (int i = 0; i < 5; ++i) {
                h8_t vf = *(const h8_t*)(vbb + ((16 * i + l16) << 7) + xsw);
                acc[i] = MFMA16x32(ap, vf, acc[i]);
            }
        }
        __builtin_amdgcn_s_setprio(0);
    }
    l_run += __shfl_xor(l_run, 16);
    l_run += __shfl_xor(l_run, 32);
    float* hc = hacc + (size_t)h2 * 8192 * 132;
    if (cs == 0 && q == 0)
        lsum[h2 * 8192 + b * 2048 + n0 + w * 16 + l16] = l_run;
    #pragma unroll
    for (int i = 0; i < 5; ++i) {
        int vc = 16 * (nbase + i) + l16;
        if (vc < 132) {
            #pragma unroll
            for (int r = 0; r < 4; ++r) {
                int grow = b * 2048 + n0 + w * 16 + 4 * q + r;
                hc[grow * 132 + vc] = acc[i][r];
            }
        }
    }
}

// ---------------- fused gates: GEMM1 (r,u) -> LDS -> GEMM2 (c) -> out --------
__global__ __launch_bounds__(256) void gate_fused(
    const float* __restrict__ hacc, const float* __restrict__ lsum,
    const int* __restrict__ nodes, const float* __restrict__ qv,
    const _Float16* __restrict__ WtRu, const _Float16* __restrict__ WtC,
    const float* __restrict__ hbuf, const float* __restrict__ x,
    float* __restrict__ out) {
    __shared__ _Float16 selh[16 * 152];
    __shared__ _Float16 selh2[16 * 152];
    __shared__ float qvs[16 * 17];
    __shared__ float invl[32];
    __shared__ float hslds[16 * 66];
    __shared__ float ulds[16 * 66];
    int t = threadIdx.x;
    int k0 = blockIdx.x * 16;
    if (t < 32) {
        int r = t >> 1, hh = t & 1;
        int grow = nodes[k0 + r];
        invl[t] = 0.5f / lsum[hh * 8192 + grow];
    }
    __syncthreads();
    // stage selh (normalized head-mean) + selh2 x-part + qvs
    for (int idx = t; idx < 16 * 136; idx += 256) {
        int r = idx / 136, c = idx % 136;
        _Float16 v = (_Float16)0.f;
        if (c < 132) {
            int grow = nodes[k0 + r];
            v = (_Float16)(hacc[grow * 132 + c] * invl[r * 2] +
                           hacc[8192 * 132 + grow * 132 + c] * invl[r * 2 + 1]);
        }
        selh[r * 152 + c] = v;
    }
    for (int idx = t; idx < 16 * 136; idx += 256) {
        int r = idx / 136, c = idx % 136;
        _Float16 v = (_Float16)0.f;
        if (c < 65) v = (_Float16)x[nodes[k0 + r] * 65 + c];
        selh2[r * 152 + c] = v;     // cols 65..135 filled/zeroed after GEMM1
    }
    if (t < 256) {
        int r = t >> 4, q = t & 15;
        qvs[r * 17 + q] = qv[(k0 + r) * 16 + q];
    }
    __syncthreads();
    int lane = t & 63, w = t >> 6;
    int l16 = lane & 15, quad = lane >> 4;
    // ---- GEMM1: r,u (128 cols; wave w owns ct 2w, 2w+1) ----
    f4_t acc0, acc1;
    acc0[0]=0.f;acc0[1]=0.f;acc0[2]=0.f;acc0[3]=0.f;
    acc1[0]=0.f;acc1[1]=0.f;acc1[2]=0.f;acc1[3]=0.f;
    const _Float16* wp0 = WtRu + ((size_t)(2 * w) * 64 + lane) * 8;
    const _Float16* wp1 = wp0 + 512;
    for (int step = 0; step < 69; ++step) {
        h8_t a;
        if (step < 68) {
            int chunk = 4 * step + quad;
            int q = chunk / 17;
            int c0 = (chunk - q * 17) * 8;
            h8_t s8 = *(const h8_t*)(selh + l16 * 152 + c0);
            _Float16 qh = (_Float16)qvs[l16 * 17 + q];
            #pragma unroll
            for (int j = 0; j < 8; ++j) a[j] = s8[j] * qh;
        } else {
            int kl = quad * 8;
            #pragma unroll
            for (int j = 0; j < 8; ++j) {
                int kq = kl + j;
                a[j] = (kq < 16) ? (_Float16)qvs[l16 * 17 + kq] : (_Float16)0.f;
            }
        }
        h8_t b0 = *(const h8_t*)(wp0 + (size_t)step * 4096);
        h8_t b1 = *(const h8_t*)(wp1 + (size_t)step * 4096);
        acc0 = MFMA16x32(a, b0, acc0);
        acc1 = MFMA16x32(a, b1, acc1);
    }
    // epilogue GEMM1 -> LDS (hsel f32 + fp16 into selh2, u f32)
    #pragma unroll
    for (int tt = 0; tt < 2; ++tt) {
        f4_t ac = tt ? acc1 : acc0;
        int o = (2 * w + tt) * 16 + l16;
        #pragma unroll
        for (int r = 0; r < 4; ++r) {
            int row = quad * 4 + r;
            float sg = 1.f / (1.f + __expf(-ac[r]));
            if (o < 64) {
                float hs = sg * hbuf[nodes[k0 + row] * 64 + o];
                hslds[row * 66 + o] = hs;
                selh2[row * 152 + 65 + o] = (_Float16)hs;
            } else {
                ulds[row * 66 + (o - 64)] = sg;
            }
        }
    }
    // zero selh2 cols 129..135 (read by last A-chunk)
    if (t < 112) {
        int r = t / 7, c = 129 + (t % 7);
        selh2[r * 152 + c] = (_Float16)0.f;
    }
    __syncthreads();
    // ---- GEMM2: c (64 cols; wave w owns ct w) ----
    f4_t acc2;
    acc2[0]=0.f;acc2[1]=0.f;acc2[2]=0.f;acc2[3]=0.f;
    const _Float16* wp = WtC + ((size_t)w * 64 + lane) * 8;
    for (int step = 0; step < 69; ++step) {
        h8_t a;
        if (step < 68) {
            int chunk = 4 * step + quad;
            int q = chunk / 17;
            int c0 = (chunk - q * 17) * 8;
            h8_t s8 = *(const h8_t*)(selh2 + l16 * 152 + c0);
            _Float16 qh = (_Float16)qvs[l16 * 17 + q];
            #pragma unroll
            for (int j = 0; j < 8; ++j) a[j] = s8[j] * qh;
        } else {
            int kl = quad * 8;
            #pragma unroll
            for (int j = 0; j < 8; ++j) {
                int kq = kl + j;
                a[j] = (kq < 16) ? (_Float16)qvs[l16 * 17 + kq] : (_Float16)0.f;
            }
        }
        h8_t b = *(const h8_t*)(wp + (size_t)step * 2048);
        acc2 = MFMA16x32(a, b, acc2);
    }
    int o = w * 16 + l16;
    #pragma unroll
    for (int r = 0; r < 4; ++r) {
        int row = quad * 4 + r;
        float cv = tanhf(acc2[r]);
        float hs = hslds[row * 66 + o];
        float uv = ulds[row * 66 + o];
        out[(k0 + row) * 64 + o] = (1.f - uv) * hs + uv * cv;
    }
}

extern "C" void kernel_launch(void* const* d_in, const int* in_sizes, int n_in,
                              void* d_out, int out_size, void* d_ws, size_t ws_size,
                              hipStream_t stream) {
    const float* x   = (const float*)d_in[0];
    const float* h   = (const float*)d_in[1];
    const float* qv  = (const float*)d_in[2];
    const int*   adj = (const int*)d_in[3];
    const int*   nod = (const int*)d_in[4];
    const float* Wq  = (const float*)d_in[5];
    const float* bq  = (const float*)d_in[6];
    const float* Wk  = (const float*)d_in[7];
    const float* bk  = (const float*)d_in[8];
    const float* Wv  = (const float*)d_in[9];
    const float* bv  = (const float*)d_in[10];
    const float* Wr  = (const float*)d_in[11];
    const float* br  = (const float*)d_in[12];
    const float* Wu  = (const float*)d_in[13];
    const float* bu  = (const float*)d_in[14];
    const float* Wc  = (const float*)d_in[15];
    const float* bc  = (const float*)d_in[16];

    char* wsb = (char*)d_ws;
    _Float16* qg   = (_Float16*)(wsb + OB_QG);
    _Float16* kg   = (_Float16*)(wsb + OB_KG);
    _Float16* vT   = (_Float16*)(wsb + OB_VT);
    unsigned* mask = (unsigned*)(wsb + OB_MASK);
    _Float16* Wall = (_Float16*)(wsb + OB_WALL);
    float* hacc    = (float*)(wsb + OB_HACC);
    float* lsum    = (float*)(wsb + OB_LSUM);
    _Float16* WtRu = (_Float16*)(wsb + OB_WTRU);
    _Float16* WtC  = (_Float16*)(wsb + OB_WTC);

    pack_adj<<<dim3(2048), 256, 0, stream>>>(adj, mask);
    repack_all<<<dim3(234), 256, 0, stream>>>(Wq, bq, Wk, bk, Wv, bv,
                                              Wr, br, Wu, bu, Wc, bc,
                                              Wall, WtRu, WtC);
    qkv_mfma<<<dim3(512), 256, 0, stream>>>(x, h, Wall, qg, kg, vT);
    attn_fused<<<dim3(64, 8, 1), 256, 0, stream>>>(qg, kg, vT, mask,
                                                   hacc, lsum, 32);
    gate_fused<<<dim3(512), 256, 0, stream>>>(hacc, lsum, nod, qv,
                                              WtRu, WtC, h, x,
                                              (float*)d_out);
}

// Round 9
// 323.320 us; speedup vs baseline: 1.0029x; 1.0029x over previous
//
#include <hip/hip_runtime.h>
#include <hip/hip_bf16.h>

// AGATCellWithMLP: B=8,N=2048,D=64,Q=16,H=2,C=129,C8=16,K=8192.
// Round 22: phase-fused attn. r13-r21 data: non-atomic attn time ~55-57us at
// BOTH 4 and 16 waves/CU -> the per-wave serial chain (QK->softmax->pT->
// barrier->PV) is the floor, not TLP, not memory. Now ONE region per tile:
// barrier -> issue DMA(mt+1)+kpre(mt+1) -> PV(mt) -> QK(mt+1)+softmax(mt+1).
// PV's ds_read/MFMA and QK's independent MFMA + softmax VALU interleave in
// one scheduling region; kpre issued at phase top is consumed at phase
// bottom (covered by PV). pT double-buffered per-wave (PV reads pT[mt&1],
// softmax writes pT[(mt+1)&1]). Still 1 barrier/tile, 0 atomics, dbuf gll V,
// XOR involution, column-split (2 blocks/CU), XCD swizzle. r21's kpre
// reorder reverted (regressed 6.6us).

typedef _Float16 h2_t __attribute__((ext_vector_type(2)));
typedef _Float16 h8_t __attribute__((ext_vector_type(8)));
typedef float    f4_t __attribute__((ext_vector_type(4)));
#define MFMA16x32(a,b,c) __builtin_amdgcn_mfma_f32_16x16x32_f16(a,b,c,0,0,0)

// ---- workspace layout (byte offsets; total 17,536,000 <= proven 22,025,248) --
#define OB_QG    0          // fp16 [2][8192][16]   524288
#define OB_KG    524288     // fp16 [2][8192][16]   524288
#define OB_VT    1048576    // fp16 [2][144][8192]  4718592
#define OB_MASK  5767168    // u32  [4][2048][64]   2097152
#define OB_WALL  7864320    // fp16 swz             107520
#define OB_HACC  7971840    // f32  [2][8192][132]  8650752 (+ lsum contiguous)
#define OB_LSUM  16622592   // f32  [2][8192]       65536
#define OB_WTRU  16688128   // fp16 swz [69][8][64][8]  565248
#define OB_WTC   17253376   // fp16 swz [69][4][64][8]  282624

// ---------------- pack_adj: first 4 batches of adj -> bitmask ----------------
__global__ __launch_bounds__(256) void pack_adj(const int* __restrict__ adj,
                                                unsigned* __restrict__ mask) {
    long tg = (long)blockIdx.x * 256 + threadIdx.x;
    for (int it = 0; it < 32; ++it) {
        long i = tg + (long)it * 524288;
        int a = adj[i];
        unsigned long long bal = __ballot(a != 0);
        if ((threadIdx.x & 63) == 0)
            *(unsigned long long*)(mask + (i >> 5)) = bal;
    }
}

// ---------------- repack_all: Wall + WtRu + WtC (swizzled) -------------------
__global__ __launch_bounds__(256) void repack_all(
    const float* __restrict__ Wq, const float* __restrict__ bq,
    const float* __restrict__ Wk, const float* __restrict__ bk,
    const float* __restrict__ Wv, const float* __restrict__ bv,
    const float* __restrict__ Wr, const float* __restrict__ br,
    const float* __restrict__ Wu, const float* __restrict__ bu,
    const float* __restrict__ Wc, const float* __restrict__ bc,
    _Float16* __restrict__ Wall, _Float16* __restrict__ WtRu,
    _Float16* __restrict__ WtC) {
    int idx = blockIdx.x * 256 + threadIdx.x;   // 6720 + 35328 + 17664 = 59712
    if (idx < 6720) {
        int ct = idx / 320;
        int rem = idx % 320;
        int s = rem >> 6, lane = rem & 63;
        int n = ct * 16 + (lane & 15);
        int quad = lane >> 4;
        int h2 = (n >= 164) ? 1 : 0;
        int nn = n - h2 * 164;
        h8_t v;
        #pragma unroll
        for (int j = 0; j < 8; ++j) {
            int k = s * 32 + quad * 8 + j;
            float f = 0.f;
            if (n < 328) {
                if (nn < 16) {
                    if (k < 129)       f = Wq[(h2 * 129 + k) * 16 + nn];
                    else if (k == 129) f = bq[h2 * 16 + nn];
                } else if (nn < 32) {
                    int d = nn - 16;
                    if (k < 129)       f = Wk[(h2 * 129 + k) * 16 + d];
                    else if (k == 129) f = bk[h2 * 16 + d];
                } else {
                    int vc = nn - 32;
                    if (vc < 129) {
                        if (k < 129)       f = Wv[(h2 * 129 + k) * 129 + vc];
                        else if (k == 129) f = bv[h2 * 129 + vc];
                    }
                }
            }
            v[j] = (_Float16)f;
        }
        *(h8_t*)(Wall + (size_t)idx * 8) = v;
    } else if (idx < 6720 + 35328) {
        int i2 = idx - 6720;
        int s = i2 / 512;
        int rem = i2 % 512;
        int ct = rem >> 6, lane = rem & 63;
        int o = ct * 16 + (lane & 15);
        int quad = lane >> 4;
        const float* W = (o < 64) ? Wr : Wu;
        const float* bb = (o < 64) ? br : bu;
        int oc = o & 63;
        h8_t v;
        #pragma unroll
        for (int j = 0; j < 8; ++j) {
            int kk = s * 32 + quad * 8 + j;
            float f = 0.f;
            if (kk < 2176) {
                int q = kk / 136, c = kk % 136;
                if (c < 129) f = W[(q * 129 + c) * 64 + oc];
            } else if (kk < 2192) {
                f = bb[(kk - 2176) * 64 + oc];
            }
            v[j] = (_Float16)f;
        }
        *(h8_t*)(WtRu + (size_t)i2 * 8) = v;
    } else if (idx < 59712) {
        int i2 = idx - 6720 - 35328;
        int s = i2 / 256;
        int rem = i2 % 256;
        int ct = rem >> 6, lane = rem & 63;
        int o = ct * 16 + (lane & 15);
        int quad = lane >> 4;
        h8_t v;
        #pragma unroll
        for (int j = 0; j < 8; ++j) {
            int kk = s * 32 + quad * 8 + j;
            float f = 0.f;
            if (kk < 2176) {
                int q = kk / 136, c = kk % 136;
                if (c < 129) f = Wc[(q * 129 + c) * 64 + o];
            } else if (kk < 2192) {
                f = bc[(kk - 2176) * 64 + o];
            }
            v[j] = (_Float16)f;
        }
        *(h8_t*)(WtC + (size_t)i2 * 8) = v;
    }
}

// ---------------- qkv via MFMA; v staged in LDS -> coalesced vT stores -------
__global__ __launch_bounds__(256) void qkv_mfma(
    const float* __restrict__ x, const float* __restrict__ h,
    const _Float16* __restrict__ Wall,
    _Float16* __restrict__ qg, _Float16* __restrict__ kg,
    _Float16* __restrict__ vT) {
    __shared__ _Float16 at[16 * 168];
    __shared__ _Float16 vls[264 * 16];   // [vcol][row] fp16
    int t = threadIdx.x;
    int row0 = blockIdx.x * 16;
    for (int idx = t; idx < 16 * 160; idx += 256) {
        int r = idx / 160, c = idx % 160;
        int grow = row0 + r;
        float v = 0.f;
        if (c < 65)       v = x[grow * 65 + c];
        else if (c < 129) v = h[grow * 64 + (c - 65)];
        else if (c == 129) v = 1.0f;
        at[r * 168 + c] = (_Float16)v;
    }
    __syncthreads();
    int lane = t & 63, w = t >> 6;
    int l16 = lane & 15, quad = lane >> 4;
    for (int ct = w; ct < 21; ct += 4) {
        f4_t acc; acc[0]=0.f; acc[1]=0.f; acc[2]=0.f; acc[3]=0.f;
        int n = ct * 16 + l16;
        const _Float16* wp = Wall + ((size_t)ct * 320 + lane) * 8;
        #pragma unroll
        for (int s = 0; s < 5; ++s) {
            h8_t a = *(const h8_t*)(at + l16 * 168 + s * 32 + quad * 8);
            h8_t b = *(const h8_t*)(wp + (size_t)s * 512);
            acc = MFMA16x32(a, b, acc);
        }
        if (n < 328) {
            int h2 = (n >= 164) ? 1 : 0;
            int nn = n - h2 * 164;
            #pragma unroll
            for (int r = 0; r < 4; ++r) {
                int row = quad * 4 + r;
                _Float16 v = (_Float16)acc[r];
                if (nn < 16)      qg[(h2 * 8192 + row0 + row) * 16 + nn] = v;
                else if (nn < 32) kg[(h2 * 8192 + row0 + row) * 16 + (nn - 16)] = v;
                else              vls[(h2 * 132 + (nn - 32)) * 16 + row] = v;
            }
        }
    }
    __syncthreads();
    // flush v: 264 cols x 16 rows as 2 x 16B bursts per col
    for (int idx = t; idx < 528; idx += 256) {
        int col = idx >> 1, half = idx & 1;
        int h2 = (col >= 132) ? 1 : 0;
        int cc = col - h2 * 132;
        uint4 v = ((const uint4*)vls)[idx];
        *(uint4*)(vT + ((size_t)(h2 * 144 + cc)) * 8192 + row0 + half * 8) = v;
    }
}

// --- attention: phase-fused PV(mt) || QK/softmax(mt+1), 1 barrier/tile (r22) -
__global__ __launch_bounds__(256) void attn_fused(
    const _Float16* __restrict__ qg, const _Float16* __restrict__ kg,
    const _Float16* __restrict__ vT, const unsigned* __restrict__ mask,
    float* __restrict__ hacc, float* __restrict__ lsum, int ntiles) {
    __shared__ _Float16 vsm[2 * 5120];      // dbuf V; 10 chunks x 1KB per buf
    __shared__ _Float16 pT[2 * 4 * 16 * 88]; // dbuf P (per-wave halves)
    int t = threadIdx.x;
    // 512 blocks: pid&7 = XCD = hb (slice L2-resident); j = pid>>3:
    // nt = j&31 (q-tile), cs = j>>5 (column split half).
    int pid = blockIdx.x + 64 * blockIdx.y;
    int hb = pid & 7, j = pid >> 3;
    int nt = j & 31, cs = j >> 5;
    int h2 = hb >> 2, b = hb & 3;
    int base = h2 * 8192 + b * 2048;
    int n0 = nt * 64;
    int nbase = cs ? 5 : 0;              // first nb owned by this block
    int jj0 = cs ? 10 : 0, jjN = cs ? 18 : 10;   // staged V chunk range
    int lane = t & 63, w = t >> 6;
    int l16 = lane & 15, q = lane >> 4;
    int qrow = n0 + w * 16 + l16;
    _Float16* pTw = pT + w * 16 * 88;    // + (mt&1)*5632 for the tile's buf
    h8_t zero8;
    #pragma unroll
    for (int i = 0; i < 8; ++i) zero8[i] = (_Float16)0.f;
    h8_t qf = zero8;
    if (q < 2) qf = *(const h8_t*)(qg + (base + qrow) * 16 + 8 * q);
    const unsigned* mrw = mask + (b * 2048 + qrow) * 64;
    f4_t acc[5];
    #pragma unroll
    for (int i = 0; i < 5; ++i) { acc[i][0]=0.f; acc[i][1]=0.f; acc[i][2]=0.f; acc[i][3]=0.f; }
    float l_run = 0.f;

    // gll staging: LOCAL chunk s = jj-jj0 covers local rows 8s..8s+7. Lane L
    // writes slot byte s*1024+16L; stored key-chunk (L&7)^(L>>3) = involution
    // with read-side XOR on (local_row&7).
    int vcol_l = (lane >> 3);
    int kch_l  = (lane & 7) ^ vcol_l;
    const _Float16* vtb = vT + (size_t)h2 * 144 * 8192 + b * 2048 + 8 * kch_l;

    h8_t kpre[4];
    uint2 mpre;
    // ---- prologue: DMA(0)->buf0; kpre/mpre(0); QK(0)+softmax(0)->pT[0] ----
    for (int jj = jj0 + w; jj < jjN; jj += 4)
        __builtin_amdgcn_global_load_lds(
            (const void*)(vtb + (size_t)(8 * jj + vcol_l) * 8192),
            (void*)(vsm + (jj - jj0) * 512), 16, 0, 0);
    #pragma unroll
    for (int ct = 0; ct < 4; ++ct) {
        kpre[ct] = zero8;
        if (q < 2)
            kpre[ct] = *(const h8_t*)(kg + (base + 16 * ct + l16) * 16 + 8 * q);
    }
    mpre = *(const uint2*)mrw;
    {
        f4_t st[4];
        #pragma unroll
        for (int ct = 0; ct < 4; ++ct) {
            f4_t z4; z4[0]=0.f; z4[1]=0.f; z4[2]=0.f; z4[3]=0.f;
            st[ct] = MFMA16x32(kpre[ct], qf, z4);
        }
        #pragma unroll
        for (int ct = 0; ct < 4; ++ct) {
            unsigned wb = (ct < 2) ? mpre.x : mpre.y;
            float p[4];
            #pragma unroll
            for (int r = 0; r < 4; ++r) {
                float sc = st[ct][r] * 0.25f;
                sc = sc > 0.f ? sc : 0.2f * sc;
                int bit = ((ct & 1) ? 16 : 0) + 4 * q + r;
                p[r] = ((wb >> bit) & 1u) ? __expf(sc) : 0.f;
                l_run += p[r];
            }
            h2_t p01; p01[0] = (_Float16)p[0]; p01[1] = (_Float16)p[1];
            h2_t p23; p23[0] = (_Float16)p[2]; p23[1] = (_Float16)p[3];
            *(h2_t*)(pTw + l16 * 88 + 16 * ct + 4 * q)     = p01;
            *(h2_t*)(pTw + l16 * 88 + 16 * ct + 4 * q + 2) = p23;
        }
    }

    for (int mt = 0; mt < ntiles; ++mt) {
        int cur = mt & 1;
        // barrier: drains DMA(mt) into buf cur (issued one phase ago);
        // confirms PV(mt-1) readers done on buf cur^1. No other loads pending.
        __syncthreads();
        if (mt + 1 < ntiles) {
            int m1 = (mt + 1) * 64;
            // DMA(mt+1) into the buffer PV(mt-1) just released
            for (int jj = jj0 + w; jj < jjN; jj += 4)
                __builtin_amdgcn_global_load_lds(
                    (const void*)(vtb + (size_t)(8 * jj + vcol_l) * 8192 + m1),
                    (void*)(vsm + (cur ^ 1) * 5120 + (jj - jj0) * 512), 16, 0, 0);
            // kpre/mpre(mt+1): issued here, consumed at QK below -> latency
            // covered by the PV stream in between.
            #pragma unroll
            for (int ct = 0; ct < 4; ++ct) {
                kpre[ct] = zero8;
                if (q < 2)
                    kpre[ct] = *(const h8_t*)(kg + (base + m1 + 16 * ct + l16) * 16 + 8 * q);
            }
            mpre = *(const uint2*)(mrw + (m1 >> 5));
        }
        // ---- fused region: PV(mt) then QK/softmax(mt+1); independent
        // streams, compiler interleaves. ----
        const char* vbb = (const char*)(vsm + cur * 5120);
        const _Float16* pRd = pTw + cur * 5632;
        __builtin_amdgcn_s_setprio(1);
        #pragma unroll
        for (int kh = 0; kh < 2; ++kh) {
            h8_t ap = *(const h8_t*)(pRd + l16 * 88 + 32 * kh + 8 * q);
            int xsw = (((kh << 2) + q) ^ (l16 & 7)) << 4;
            #pragma unroll
            for (int i = 0; i < 5; ++i) {
                h8_t vf = *(const h8_t*)(vbb + ((16 * i + l16) << 7) + xsw);
                acc[i] = MFMA16x32(ap, vf, acc[i]);
            }
        }
        __builtin_amdgcn_s_setprio(0);
        if (mt + 1 < ntiles) {
            _Float16* pWr = pTw + (cur ^ 1) * 5632;
            f4_t st[4];
            #pragma unroll
            for (int ct = 0; ct < 4; ++ct) {
                f4_t z4; z4[0]=0.f; z4[1]=0.f; z4[2]=0.f; z4[3]=0.f;
                st[ct] = MFMA16x32(kpre[ct], qf, z4);
            }
            #pragma unroll
            for (int ct = 0; ct < 4; ++ct) {
                unsigned wb = (ct < 2) ? mpre.x : mpre.y;
                float p[4];
                #pragma unroll
                for (int r = 0; r < 4; ++r) {
                    float sc = st[ct][r] * 0.25f;
                    sc = sc > 0.f ? sc : 0.2f * sc;
                    int bit = ((ct & 1) ? 16 : 0) + 4 * q + r;
                    p[r] = ((wb >> bit) & 1u) ? __expf(sc) : 0.f;
                    l_run += p[r];
                }
                h2_t p01; p01[0] = (_Float16)p[0]; p01[1] = (_Float16)p[1];
                h2_t p23; p23[0] = (_Float16)p[2]; p23[1] = (_Float16)p[3];
                *(h2_t*)(pWr + l16 * 88 + 16 * ct + 4 * q)     = p01;
                *(h2_t*)(pWr + l16 * 88 + 16 * ct + 4 * q + 2) = p23;
            }
        }
    }
    l_run += __shfl_xor(l_run, 16);
    l_run += __shfl_xor(l_run, 32);
    float* hc = hacc + (size_t)h2 * 8192 * 132;
    if (cs == 0 && q == 0)
        lsum[h2 * 8192 + b * 2048 + n0 + w * 16 + l16] = l_run;
    #pragma unroll
    for (int i = 0; i < 5; ++i) {
        int vc = 16 * (nbase + i) + l16;
        if (vc < 132) {
            #pragma unroll
            for (int r = 0; r < 4; ++r) {
                int grow = b * 2048 + n0 + w * 16 + 4 * q + r;
                hc[grow * 132 + vc] = acc[i][r];
            }
        }
    }
}

// ---------------- fused gates: GEMM1 (r,u) -> LDS -> GEMM2 (c) -> out --------
__global__ __launch_bounds__(256) void gate_fused(
    const float* __restrict__ hacc, const float* __restrict__ lsum,
    const int* __restrict__ nodes, const float* __restrict__ qv,
    const _Float16* __restrict__ WtRu, const _Float16* __restrict__ WtC,
    const float* __restrict__ hbuf, const float* __restrict__ x,
    float* __restrict__ out) {
    __shared__ _Float16 selh[16 * 152];
    __shared__ _Float16 selh2[16 * 152];
    __shared__ float qvs[16 * 17];
    __shared__ float invl[32];
    __shared__ float hslds[16 * 66];
    __shared__ float ulds[16 * 66];
    int t = threadIdx.x;
    int k0 = blockIdx.x * 16;
    if (t < 32) {
        int r = t >> 1, hh = t & 1;
        int grow = nodes[k0 + r];
        invl[t] = 0.5f / lsum[hh * 8192 + grow];
    }
    __syncthreads();
    // stage selh (normalized head-mean) + selh2 x-part + qvs
    for (int idx = t; idx < 16 * 136; idx += 256) {
        int r = idx / 136, c = idx % 136;
        _Float16 v = (_Float16)0.f;
        if (c < 132) {
            int grow = nodes[k0 + r];
            v = (_Float16)(hacc[grow * 132 + c] * invl[r * 2] +
                           hacc[8192 * 132 + grow * 132 + c] * invl[r * 2 + 1]);
        }
        selh[r * 152 + c] = v;
    }
    for (int idx = t; idx < 16 * 136; idx += 256) {
        int r = idx / 136, c = idx % 136;
        _Float16 v = (_Float16)0.f;
        if (c < 65) v = (_Float16)x[nodes[k0 + r] * 65 + c];
        selh2[r * 152 + c] = v;     // cols 65..135 filled/zeroed after GEMM1
    }
    if (t < 256) {
        int r = t >> 4, q = t & 15;
        qvs[r * 17 + q] = qv[(k0 + r) * 16 + q];
    }
    __syncthreads();
    int lane = t & 63, w = t >> 6;
    int l16 = lane & 15, quad = lane >> 4;
    // ---- GEMM1: r,u (128 cols; wave w owns ct 2w, 2w+1) ----
    f4_t acc0, acc1;
    acc0[0]=0.f;acc0[1]=0.f;acc0[2]=0.f;acc0[3]=0.f;
    acc1[0]=0.f;acc1[1]=0.f;acc1[2]=0.f;acc1[3]=0.f;
    const _Float16* wp0 = WtRu + ((size_t)(2 * w) * 64 + lane) * 8;
    const _Float16* wp1 = wp0 + 512;
    for (int step = 0; step < 69; ++step) {
        h8_t a;
        if (step < 68) {
            int chunk = 4 * step + quad;
            int q = chunk / 17;
            int c0 = (chunk - q * 17) * 8;
            h8_t s8 = *(const h8_t*)(selh + l16 * 152 + c0);
            _Float16 qh = (_Float16)qvs[l16 * 17 + q];
            #pragma unroll
            for (int j = 0; j < 8; ++j) a[j] = s8[j] * qh;
        } else {
            int kl = quad * 8;
            #pragma unroll
            for (int j = 0; j < 8; ++j) {
                int kq = kl + j;
                a[j] = (kq < 16) ? (_Float16)qvs[l16 * 17 + kq] : (_Float16)0.f;
            }
        }
        h8_t b0 = *(const h8_t*)(wp0 + (size_t)step * 4096);
        h8_t b1 = *(const h8_t*)(wp1 + (size_t)step * 4096);
        acc0 = MFMA16x32(a, b0, acc0);
        acc1 = MFMA16x32(a, b1, acc1);
    }
    // epilogue GEMM1 -> LDS (hsel f32 + fp16 into selh2, u f32)
    #pragma unroll
    for (int tt = 0; tt < 2; ++tt) {
        f4_t ac = tt ? acc1 : acc0;
        int o = (2 * w + tt) * 16 + l16;
        #pragma unroll
        for (int r = 0; r < 4; ++r) {
            int row = quad * 4 + r;
            float sg = 1.f / (1.f + __expf(-ac[r]));
            if (o < 64) {
                float hs = sg * hbuf[nodes[k0 + row] * 64 + o];
                hslds[row * 66 + o] = hs;
                selh2[row * 152 + 65 + o] = (_Float16)hs;
            } else {
                ulds[row * 66 + (o - 64)] = sg;
            }
        }
    }
    // zero selh2 cols 129..135 (read by last A-chunk)
    if (t < 112) {
        int r = t / 7, c = 129 + (t % 7);
        selh2[r * 152 + c] = (_Float16)0.f;
    }
    __syncthreads();
    // ---- GEMM2: c (64 cols; wave w owns ct w) ----
    f4_t acc2;
    acc2[0]=0.f;acc2[1]=0.f;acc2[2]=0.f;acc2[3]=0.f;
    const _Float16* wp = WtC + ((size_t)w * 64 + lane) * 8;
    for (int step = 0; step < 69; ++step) {
        h8_t a;
        if (step < 68) {
            int chunk = 4 * step + quad;
            int q = chunk / 17;
            int c0 = (chunk - q * 17) * 8;
            h8_t s8 = *(const h8_t*)(selh2 + l16 * 152 + c0);
            _Float16 qh = (_Float16)qvs[l16 * 17 + q];
            #pragma unroll
            for (int j = 0; j < 8; ++j) a[j] = s8[j] * qh;
        } else {
            int kl = quad * 8;
            #pragma unroll
            for (int j = 0; j < 8; ++j) {
                int kq = kl + j;
                a[j] = (kq < 16) ? (_Float16)qvs[l16 * 17 + kq] : (_Float16)0.f;
            }
        }
        h8_t b = *(const h8_t*)(wp + (size_t)step * 2048);
        acc2 = MFMA16x32(a, b, acc2);
    }
    int o = w * 16 + l16;
    #pragma unroll
    for (int r = 0; r < 4; ++r) {
        int row = quad * 4 + r;
        float cv = tanhf(acc2[r]);
        float hs = hslds[row * 66 + o];
        float uv = ulds[row * 66 + o];
        out[(k0 + row) * 64 + o] = (1.f - uv) * hs + uv * cv;
    }
}

extern "C" void kernel_launch(void* const* d_in, const int* in_sizes, int n_in,
                              void* d_out, int out_size, void* d_ws, size_t ws_size,
                              hipStream_t stream) {
    const float* x   = (const float*)d_in[0];
    const float* h   = (const float*)d_in[1];
    const float* qv  = (const float*)d_in[2];
    const int*   adj = (const int*)d_in[3];
    const int*   nod = (const int*)d_in[4];
    const float* Wq  = (const float*)d_in[5];
    const float* bq  = (const float*)d_in[6];
    const float* Wk  = (const float*)d_in[7];
    const float* bk  = (const float*)d_in[8];
    const float* Wv  = (const float*)d_in[9];
    const float* bv  = (const float*)d_in[10];
    const float* Wr  = (const float*)d_in[11];
    const float* br  = (const float*)d_in[12];
    const float* Wu  = (const float*)d_in[13];
    const float* bu  = (const float*)d_in[14];
    const float* Wc  = (const float*)d_in[15];
    const float* bc  = (const float*)d_in[16];

    char* wsb = (char*)d_ws;
    _Float16* qg   = (_Float16*)(wsb + OB_QG);
    _Float16* kg   = (_Float16*)(wsb + OB_KG);
    _Float16* vT   = (_Float16*)(wsb + OB_VT);
    unsigned* mask = (unsigned*)(wsb + OB_MASK);
    _Float16* Wall = (_Float16*)(wsb + OB_WALL);
    float* hacc    = (float*)(wsb + OB_HACC);
    float* lsum    = (float*)(wsb + OB_LSUM);
    _Float16* WtRu = (_Float16*)(wsb + OB_WTRU);
    _Float16* WtC  = (_Float16*)(wsb + OB_WTC);

    pack_adj<<<dim3(2048), 256, 0, stream>>>(adj, mask);
    repack_all<<<dim3(234), 256, 0, stream>>>(Wq, bq, Wk, bk, Wv, bv,
                                              Wr, br, Wu, bu, Wc, bc,
                                              Wall, WtRu, WtC);
    qkv_mfma<<<dim3(512), 256, 0, stream>>>(x, h, Wall, qg, kg, vT);
    attn_fused<<<dim3(64, 8, 1), 256, 0, stream>>>(qg, kg, vT, mask,
                                                   hacc, lsum, 32);
    gate_fused<<<dim3(512), 256, 0, stream>>>(hacc, lsum, nod, qv,
                                              WtRu, WtC, h, x,
                                              (float*)d_out);
}

// Round 10
// 322.572 us; speedup vs baseline: 1.0052x; 1.0023x over previous
//
#include <hip/hip_runtime.h>
#include <hip/hip_bf16.h>

// AGATCellWithMLP: B=8,N=2048,D=64,Q=16,H=2,C=129,C8=16,K=8192.
// Round 23: r20 EXACT structure (best: 317.6us; r21/r22 schedule tweaks both
// regressed ~6) with the split widened 2->3: each (hb,nt) has cs in {0,1,2}
// owning 3 nb (48 V-cols, 6 gll chunks). 768 blocks = 3 blocks/CU = 12
// waves/CU. The only lever that has worked post-atomics is independent
// co-resident blocks (r19->r20: +1 block = -5us); QK/softmax triplication is
// ~250cy of a ~4100cy tile wall, kg/mask re-reads are L2 hits (r16 FETCH
// evidence). LDS 23.3KB/block. cs=2's nb=8 tail reads vT's uninit cols
// 132-143; discarded by the vc<132 store guard (same as r20's dummy nb).

typedef _Float16 h2_t __attribute__((ext_vector_type(2)));
typedef _Float16 h8_t __attribute__((ext_vector_type(8)));
typedef float    f4_t __attribute__((ext_vector_type(4)));
#define MFMA16x32(a,b,c) __builtin_amdgcn_mfma_f32_16x16x32_f16(a,b,c,0,0,0)

// ---- workspace layout (byte offsets; total 17,536,000 <= proven 22,025,248) --
#define OB_QG    0          // fp16 [2][8192][16]   524288
#define OB_KG    524288     // fp16 [2][8192][16]   524288
#define OB_VT    1048576    // fp16 [2][144][8192]  4718592
#define OB_MASK  5767168    // u32  [4][2048][64]   2097152
#define OB_WALL  7864320    // fp16 swz             107520
#define OB_HACC  7971840    // f32  [2][8192][132]  8650752 (+ lsum contiguous)
#define OB_LSUM  16622592   // f32  [2][8192]       65536
#define OB_WTRU  16688128   // fp16 swz [69][8][64][8]  565248
#define OB_WTC   17253376   // fp16 swz [69][4][64][8]  282624

// ---------------- pack_adj: first 4 batches of adj -> bitmask ----------------
__global__ __launch_bounds__(256) void pack_adj(const int* __restrict__ adj,
                                                unsigned* __restrict__ mask) {
    long tg = (long)blockIdx.x * 256 + threadIdx.x;
    for (int it = 0; it < 32; ++it) {
        long i = tg + (long)it * 524288;
        int a = adj[i];
        unsigned long long bal = __ballot(a != 0);
        if ((threadIdx.x & 63) == 0)
            *(unsigned long long*)(mask + (i >> 5)) = bal;
    }
}

// ---------------- repack_all: Wall + WtRu + WtC (swizzled) -------------------
__global__ __launch_bounds__(256) void repack_all(
    const float* __restrict__ Wq, const float* __restrict__ bq,
    const float* __restrict__ Wk, const float* __restrict__ bk,
    const float* __restrict__ Wv, const float* __restrict__ bv,
    const float* __restrict__ Wr, const float* __restrict__ br,
    const float* __restrict__ Wu, const float* __restrict__ bu,
    const float* __restrict__ Wc, const float* __restrict__ bc,
    _Float16* __restrict__ Wall, _Float16* __restrict__ WtRu,
    _Float16* __restrict__ WtC) {
    int idx = blockIdx.x * 256 + threadIdx.x;   // 6720 + 35328 + 17664 = 59712
    if (idx < 6720) {
        int ct = idx / 320;
        int rem = idx % 320;
        int s = rem >> 6, lane = rem & 63;
        int n = ct * 16 + (lane & 15);
        int quad = lane >> 4;
        int h2 = (n >= 164) ? 1 : 0;
        int nn = n - h2 * 164;
        h8_t v;
        #pragma unroll
        for (int j = 0; j < 8; ++j) {
            int k = s * 32 + quad * 8 + j;
            float f = 0.f;
            if (n < 328) {
                if (nn < 16) {
                    if (k < 129)       f = Wq[(h2 * 129 + k) * 16 + nn];
                    else if (k == 129) f = bq[h2 * 16 + nn];
                } else if (nn < 32) {
                    int d = nn - 16;
                    if (k < 129)       f = Wk[(h2 * 129 + k) * 16 + d];
                    else if (k == 129) f = bk[h2 * 16 + d];
                } else {
                    int vc = nn - 32;
                    if (vc < 129) {
                        if (k < 129)       f = Wv[(h2 * 129 + k) * 129 + vc];
                        else if (k == 129) f = bv[h2 * 129 + vc];
                    }
                }
            }
            v[j] = (_Float16)f;
        }
        *(h8_t*)(Wall + (size_t)idx * 8) = v;
    } else if (idx < 6720 + 35328) {
        int i2 = idx - 6720;
        int s = i2 / 512;
        int rem = i2 % 512;
        int ct = rem >> 6, lane = rem & 63;
        int o = ct * 16 + (lane & 15);
        int quad = lane >> 4;
        const float* W = (o < 64) ? Wr : Wu;
        const float* bb = (o < 64) ? br : bu;
        int oc = o & 63;
        h8_t v;
        #pragma unroll
        for (int j = 0; j < 8; ++j) {
            int kk = s * 32 + quad * 8 + j;
            float f = 0.f;
            if (kk < 2176) {
                int q = kk / 136, c = kk % 136;
                if (c < 129) f = W[(q * 129 + c) * 64 + oc];
            } else if (kk < 2192) {
                f = bb[(kk - 2176) * 64 + oc];
            }
            v[j] = (_Float16)f;
        }
        *(h8_t*)(WtRu + (size_t)i2 * 8) = v;
    } else if (idx < 59712) {
        int i2 = idx - 6720 - 35328;
        int s = i2 / 256;
        int rem = i2 % 256;
        int ct = rem >> 6, lane = rem & 63;
        int o = ct * 16 + (lane & 15);
        int quad = lane >> 4;
        h8_t v;
        #pragma unroll
        for (int j = 0; j < 8; ++j) {
            int kk = s * 32 + quad * 8 + j;
            float f = 0.f;
            if (kk < 2176) {
                int q = kk / 136, c = kk % 136;
                if (c < 129) f = Wc[(q * 129 + c) * 64 + o];
            } else if (kk < 2192) {
                f = bc[(kk - 2176) * 64 + o];
            }
            v[j] = (_Float16)f;
        }
        *(h8_t*)(WtC + (size_t)i2 * 8) = v;
    }
}

// ---------------- qkv via MFMA; v staged in LDS -> coalesced vT stores -------
__global__ __launch_bounds__(256) void qkv_mfma(
    const float* __restrict__ x, const float* __restrict__ h,
    const _Float16* __restrict__ Wall,
    _Float16* __restrict__ qg, _Float16* __restrict__ kg,
    _Float16* __restrict__ vT) {
    __shared__ _Float16 at[16 * 168];
    __shared__ _Float16 vls[264 * 16];   // [vcol][row] fp16
    int t = threadIdx.x;
    int row0 = blockIdx.x * 16;
    for (int idx = t; idx < 16 * 160; idx += 256) {
        int r = idx / 160, c = idx % 160;
        int grow = row0 + r;
        float v = 0.f;
        if (c < 65)       v = x[grow * 65 + c];
        else if (c < 129) v = h[grow * 64 + (c - 65)];
        else if (c == 129) v = 1.0f;
        at[r * 168 + c] = (_Float16)v;
    }
    __syncthreads();
    int lane = t & 63, w = t >> 6;
    int l16 = lane & 15, quad = lane >> 4;
    for (int ct = w; ct < 21; ct += 4) {
        f4_t acc; acc[0]=0.f; acc[1]=0.f; acc[2]=0.f; acc[3]=0.f;
        int n = ct * 16 + l16;
        const _Float16* wp = Wall + ((size_t)ct * 320 + lane) * 8;
        #pragma unroll
        for (int s = 0; s < 5; ++s) {
            h8_t a = *(const h8_t*)(at + l16 * 168 + s * 32 + quad * 8);
            h8_t b = *(const h8_t*)(wp + (size_t)s * 512);
            acc = MFMA16x32(a, b, acc);
        }
        if (n < 328) {
            int h2 = (n >= 164) ? 1 : 0;
            int nn = n - h2 * 164;
            #pragma unroll
            for (int r = 0; r < 4; ++r) {
                int row = quad * 4 + r;
                _Float16 v = (_Float16)acc[r];
                if (nn < 16)      qg[(h2 * 8192 + row0 + row) * 16 + nn] = v;
                else if (nn < 32) kg[(h2 * 8192 + row0 + row) * 16 + (nn - 16)] = v;
                else              vls[(h2 * 132 + (nn - 32)) * 16 + row] = v;
            }
        }
    }
    __syncthreads();
    // flush v: 264 cols x 16 rows as 2 x 16B bursts per col
    for (int idx = t; idx < 528; idx += 256) {
        int col = idx >> 1, half = idx & 1;
        int h2 = (col >= 132) ? 1 : 0;
        int cc = col - h2 * 132;
        uint4 v = ((const uint4*)vls)[idx];
        *(uint4*)(vT + ((size_t)(h2 * 144 + cc)) * 8192 + row0 + half * 8) = v;
    }
}

// --- attention: atomic-free, 3-way column-split (3 blocks/CU), dbuf gll (r23) -
__global__ __launch_bounds__(256) void attn_fused(
    const _Float16* __restrict__ qg, const _Float16* __restrict__ kg,
    const _Float16* __restrict__ vT, const unsigned* __restrict__ mask,
    float* __restrict__ hacc, float* __restrict__ lsum, int ntiles) {
    __shared__ _Float16 vsm[2 * 3072];   // dbuf; 6 chunks x 1KB per buf
    __shared__ _Float16 pT[4 * 16 * 88];
    int t = threadIdx.x;
    // 768 blocks: pid&7 = XCD = hb (slice L2-resident); j = pid>>3 (0..95):
    // nt = j&31 (q-tile), cs = j>>5 (0..2, column third).
    int pid = blockIdx.x + 96 * blockIdx.y;
    int hb = pid & 7, j = pid >> 3;
    int nt = j & 31, cs = j >> 5;
    int h2 = hb >> 2, b = hb & 3;
    int base = h2 * 8192 + b * 2048;
    int n0 = nt * 64;
    int nbase = 3 * cs;                  // first nb owned by this block
    int jj0 = 6 * cs;                    // staged V chunk range [jj0, jj0+6)
    int lane = t & 63, w = t >> 6;
    int l16 = lane & 15, q = lane >> 4;
    int qrow = n0 + w * 16 + l16;
    _Float16* pTw = pT + w * 16 * 88;
    h8_t zero8;
    #pragma unroll
    for (int i = 0; i < 8; ++i) zero8[i] = (_Float16)0.f;
    h8_t qf = zero8;
    if (q < 2) qf = *(const h8_t*)(qg + (base + qrow) * 16 + 8 * q);
    const unsigned* mrw = mask + (b * 2048 + qrow) * 64;
    f4_t acc[3];
    #pragma unroll
    for (int i = 0; i < 3; ++i) { acc[i][0]=0.f; acc[i][1]=0.f; acc[i][2]=0.f; acc[i][3]=0.f; }
    float l_run = 0.f;

    // gll staging: LOCAL chunk s = jj-jj0 covers local rows 8s..8s+7. Lane L
    // writes slot byte s*1024+16L; stored key-chunk (L&7)^(L>>3) = involution
    // with read-side XOR on (local_row&7). cs offsets are multiples of 8 so
    // the involution is unchanged.
    int vcol_l = (lane >> 3);
    int kch_l  = (lane & 7) ^ vcol_l;
    const _Float16* vtb = vT + (size_t)h2 * 144 * 8192 + b * 2048 + 8 * kch_l;

    h8_t kpre[4];
    uint2 mpre;
    // prologue: DMA tile 0 -> buf 0; K/mask prefetch tile 0
    for (int jj = jj0 + w; jj < jj0 + 6; jj += 4)
        __builtin_amdgcn_global_load_lds(
            (const void*)(vtb + (size_t)(8 * jj + vcol_l) * 8192),
            (void*)(vsm + (jj - jj0) * 512), 16, 0, 0);
    #pragma unroll
    for (int ct = 0; ct < 4; ++ct) {
        kpre[ct] = zero8;
        if (q < 2)
            kpre[ct] = *(const h8_t*)(kg + (base + 16 * ct + l16) * 16 + 8 * q);
    }
    mpre = *(const uint2*)mrw;

    for (int mt = 0; mt < ntiles; ++mt) {
        int cur = mt & 1;
        // ---- QK + softmax (V DMA(mt) into buf cur in flight underneath) ----
        h8_t kf[4];
        #pragma unroll
        for (int ct = 0; ct < 4; ++ct) kf[ct] = kpre[ct];
        uint2 mw = mpre;
        f4_t st[4];
        #pragma unroll
        for (int ct = 0; ct < 4; ++ct) {
            f4_t z4; z4[0]=0.f; z4[1]=0.f; z4[2]=0.f; z4[3]=0.f;
            st[ct] = MFMA16x32(kf[ct], qf, z4);
        }
        #pragma unroll
        for (int ct = 0; ct < 4; ++ct) {
            unsigned wb = (ct < 2) ? mw.x : mw.y;
            float p[4];
            #pragma unroll
            for (int r = 0; r < 4; ++r) {
                float sc = st[ct][r] * 0.25f;
                sc = sc > 0.f ? sc : 0.2f * sc;
                int bit = ((ct & 1) ? 16 : 0) + 4 * q + r;
                p[r] = ((wb >> bit) & 1u) ? __expf(sc) : 0.f;
                l_run += p[r];
            }
            h2_t p01; p01[0] = (_Float16)p[0]; p01[1] = (_Float16)p[1];
            h2_t p23; p23[0] = (_Float16)p[2]; p23[1] = (_Float16)p[3];
            *(h2_t*)(pTw + l16 * 88 + 16 * ct + 4 * q)     = p01;
            *(h2_t*)(pTw + l16 * 88 + 16 * ct + 4 * q + 2) = p23;
        }
        // prefetch next tile's K/mask (consumed next iteration) — r20 order
        if (mt + 1 < ntiles) {
            int m1 = (mt + 1) * 64;
            #pragma unroll
            for (int ct = 0; ct < 4; ++ct) {
                kpre[ct] = zero8;
                if (q < 2)
                    kpre[ct] = *(const h8_t*)(kg + (base + m1 + 16 * ct + l16) * 16 + 8 * q);
            }
            mpre = *(const uint2*)(mrw + (m1 >> 5));
        }
        // ONE barrier: per-wave vmcnt(0) drain completes DMA(mt); also all
        // waves finished PV(mt-1) on buf cur^1 -> safe to DMA into it.
        __syncthreads();
        if (mt + 1 < ntiles) {
            int m1 = (mt + 1) * 64;
            for (int jj = jj0 + w; jj < jj0 + 6; jj += 4)
                __builtin_amdgcn_global_load_lds(
                    (const void*)(vtb + (size_t)(8 * jj + vcol_l) * 8192 + m1),
                    (void*)(vsm + (cur ^ 1) * 3072 + (jj - jj0) * 512), 16, 0, 0);
        }
        // ---- PV on buf cur (swizzled reads; local rows 16i+l16, i<3) ----
        const char* vbb = (const char*)(vsm + cur * 3072);
        __builtin_amdgcn_s_setprio(1);
        #pragma unroll
        for (int kh = 0; kh < 2; ++kh) {
            h8_t ap = *(const h8_t*)(pTw + l16 * 88 + 32 * kh + 8 * q);
            int xsw = (((kh << 2) + q) ^ (l16 & 7)) << 4;
            #pragma unroll
            for (int i = 0; i < 3; ++i) {
                h8_t vf = *(const h8_t*)(vbb + ((16 * i + l16) << 7) + xsw);
                acc[i] = MFMA16x32(ap, vf, acc[i]);
            }
        }
        __builtin_amdgcn_s_setprio(0);
    }
    l_run += __shfl_xor(l_run, 16);
    l_run += __shfl_xor(l_run, 32);
    float* hc = hacc + (size_t)h2 * 8192 * 132;
    if (cs == 0 && q == 0)
        lsum[h2 * 8192 + b * 2048 + n0 + w * 16 + l16] = l_run;
    #pragma unroll
    for (int i = 0; i < 3; ++i) {
        int vc = 16 * (nbase + i) + l16;
        if (vc < 132) {
            #pragma unroll
            for (int r = 0; r < 4; ++r) {
                int grow = b * 2048 + n0 + w * 16 + 4 * q + r;
                hc[grow * 132 + vc] = acc[i][r];
            }
        }
    }
}

// ---------------- fused gates: GEMM1 (r,u) -> LDS -> GEMM2 (c) -> out --------
__global__ __launch_bounds__(256) void gate_fused(
    const float* __restrict__ hacc, const float* __restrict__ lsum,
    const int* __restrict__ nodes, const float* __restrict__ qv,
    const _Float16* __restrict__ WtRu, const _Float16* __restrict__ WtC,
    const float* __restrict__ hbuf, const float* __restrict__ x,
    float* __restrict__ out) {
    __shared__ _Float16 selh[16 * 152];
    __shared__ _Float16 selh2[16 * 152];
    __shared__ float qvs[16 * 17];
    __shared__ float invl[32];
    __shared__ float hslds[16 * 66];
    __shared__ float ulds[16 * 66];
    int t = threadIdx.x;
    int k0 = blockIdx.x * 16;
    if (t < 32) {
        int r = t >> 1, hh = t & 1;
        int grow = nodes[k0 + r];
        invl[t] = 0.5f / lsum[hh * 8192 + grow];
    }
    __syncthreads();
    // stage selh (normalized head-mean) + selh2 x-part + qvs
    for (int idx = t; idx < 16 * 136; idx += 256) {
        int r = idx / 136, c = idx % 136;
        _Float16 v = (_Float16)0.f;
        if (c < 132) {
            int grow = nodes[k0 + r];
            v = (_Float16)(hacc[grow * 132 + c] * invl[r * 2] +
                           hacc[8192 * 132 + grow * 132 + c] * invl[r * 2 + 1]);
        }
        selh[r * 152 + c] = v;
    }
    for (int idx = t; idx < 16 * 136; idx += 256) {
        int r = idx / 136, c = idx % 136;
        _Float16 v = (_Float16)0.f;
        if (c < 65) v = (_Float16)x[nodes[k0 + r] * 65 + c];
        selh2[r * 152 + c] = v;     // cols 65..135 filled/zeroed after GEMM1
    }
    if (t < 256) {
        int r = t >> 4, q = t & 15;
        qvs[r * 17 + q] = qv[(k0 + r) * 16 + q];
    }
    __syncthreads();
    int lane = t & 63, w = t >> 6;
    int l16 = lane & 15, quad = lane >> 4;
    // ---- GEMM1: r,u (128 cols; wave w owns ct 2w, 2w+1) ----
    f4_t acc0, acc1;
    acc0[0]=0.f;acc0[1]=0.f;acc0[2]=0.f;acc0[3]=0.f;
    acc1[0]=0.f;acc1[1]=0.f;acc1[2]=0.f;acc1[3]=0.f;
    const _Float16* wp0 = WtRu + ((size_t)(2 * w) * 64 + lane) * 8;
    const _Float16* wp1 = wp0 + 512;
    for (int step = 0; step < 69; ++step) {
        h8_t a;
        if (step < 68) {
            int chunk = 4 * step + quad;
            int q = chunk / 17;
            int c0 = (chunk - q * 17) * 8;
            h8_t s8 = *(const h8_t*)(selh + l16 * 152 + c0);
            _Float16 qh = (_Float16)qvs[l16 * 17 + q];
            #pragma unroll
            for (int j = 0; j < 8; ++j) a[j] = s8[j] * qh;
        } else {
            int kl = quad * 8;
            #pragma unroll
            for (int j = 0; j < 8; ++j) {
                int kq = kl + j;
                a[j] = (kq < 16) ? (_Float16)qvs[l16 * 17 + kq] : (_Float16)0.f;
            }
        }
        h8_t b0 = *(const h8_t*)(wp0 + (size_t)step * 4096);
        h8_t b1 = *(const h8_t*)(wp1 + (size_t)step * 4096);
        acc0 = MFMA16x32(a, b0, acc0);
        acc1 = MFMA16x32(a, b1, acc1);
    }
    // epilogue GEMM1 -> LDS (hsel f32 + fp16 into selh2, u f32)
    #pragma unroll
    for (int tt = 0; tt < 2; ++tt) {
        f4_t ac = tt ? acc1 : acc0;
        int o = (2 * w + tt) * 16 + l16;
        #pragma unroll
        for (int r = 0; r < 4; ++r) {
            int row = quad * 4 + r;
            float sg = 1.f / (1.f + __expf(-ac[r]));
            if (o < 64) {
                float hs = sg * hbuf[nodes[k0 + row] * 64 + o];
                hslds[row * 66 + o] = hs;
                selh2[row * 152 + 65 + o] = (_Float16)hs;
            } else {
                ulds[row * 66 + (o - 64)] = sg;
            }
        }
    }
    // zero selh2 cols 129..135 (read by last A-chunk)
    if (t < 112) {
        int r = t / 7, c = 129 + (t % 7);
        selh2[r * 152 + c] = (_Float16)0.f;
    }
    __syncthreads();
    // ---- GEMM2: c (64 cols; wave w owns ct w) ----
    f4_t acc2;
    acc2[0]=0.f;acc2[1]=0.f;acc2[2]=0.f;acc2[3]=0.f;
    const _Float16* wp = WtC + ((size_t)w * 64 + lane) * 8;
    for (int step = 0; step < 69; ++step) {
        h8_t a;
        if (step < 68) {
            int chunk = 4 * step + quad;
            int q = chunk / 17;
            int c0 = (chunk - q * 17) * 8;
            h8_t s8 = *(const h8_t*)(selh2 + l16 * 152 + c0);
            _Float16 qh = (_Float16)qvs[l16 * 17 + q];
            #pragma unroll
            for (int j = 0; j < 8; ++j) a[j] = s8[j] * qh;
        } else {
            int kl = quad * 8;
            #pragma unroll
            for (int j = 0; j < 8; ++j) {
                int kq = kl + j;
                a[j] = (kq < 16) ? (_Float16)qvs[l16 * 17 + kq] : (_Float16)0.f;
            }
        }
        h8_t b = *(const h8_t*)(wp + (size_t)step * 2048);
        acc2 = MFMA16x32(a, b, acc2);
    }
    int o = w * 16 + l16;
    #pragma unroll
    for (int r = 0; r < 4; ++r) {
        int row = quad * 4 + r;
        float cv = tanhf(acc2[r]);
        float hs = hslds[row * 66 + o];
        float uv = ulds[row * 66 + o];
        out[(k0 + row) * 64 + o] = (1.f - uv) * hs + uv * cv;
    }
}

extern "C" void kernel_launch(void* const* d_in, const int* in_sizes, int n_in,
                              void* d_out, int out_size, void* d_ws, size_t ws_size,
                              hipStream_t stream) {
    const float* x   = (const float*)d_in[0];
    const float* h   = (const float*)d_in[1];
    const float* qv  = (const float*)d_in[2];
    const int*   adj = (const int*)d_in[3];
    const int*   nod = (const int*)d_in[4];
    const float* Wq  = (const float*)d_in[5];
    const float* bq  = (const float*)d_in[6];
    const float* Wk  = (const float*)d_in[7];
    const float* bk  = (const float*)d_in[8];
    const float* Wv  = (const float*)d_in[9];
    const float* bv  = (const float*)d_in[10];
    const float* Wr  = (const float*)d_in[11];
    const float* br  = (const float*)d_in[12];
    const float* Wu  = (const float*)d_in[13];
    const float* bu  = (const float*)d_in[14];
    const float* Wc  = (const float*)d_in[15];
    const float* bc  = (const float*)d_in[16];

    char* wsb = (char*)d_ws;
    _Float16* qg   = (_Float16*)(wsb + OB_QG);
    _Float16* kg   = (_Float16*)(wsb + OB_KG);
    _Float16* vT   = (_Float16*)(wsb + OB_VT);
    unsigned* mask = (unsigned*)(wsb + OB_MASK);
    _Float16* Wall = (_Float16*)(wsb + OB_WALL);
    float* hacc    = (float*)(wsb + OB_HACC);
    float* lsum    = (float*)(wsb + OB_LSUM);
    _Float16* WtRu = (_Float16*)(wsb + OB_WTRU);
    _Float16* WtC  = (_Float16*)(wsb + OB_WTC);

    pack_adj<<<dim3(2048), 256, 0, stream>>>(adj, mask);
    repack_all<<<dim3(234), 256, 0, stream>>>(Wq, bq, Wk, bk, Wv, bv,
                                              Wr, br, Wu, bu, Wc, bc,
                                              Wall, WtRu, WtC);
    qkv_mfma<<<dim3(512), 256, 0, stream>>>(x, h, Wall, qg, kg, vT);
    attn_fused<<<dim3(96, 8, 1), 256, 0, stream>>>(qg, kg, vT, mask,
                                                   hacc, lsum, 32);
    gate_fused<<<dim3(512), 256, 0, stream>>>(hacc, lsum, nod, qv,
                                              WtRu, WtC, h, x,
                                              (float*)d_out);
}

// Round 11
// 313.393 us; speedup vs baseline: 1.0346x; 1.0293x over previous
//
#include <hip/hip_runtime.h>
#include <hip/hip_bf16.h>

// AGATCellWithMLP: B=8,N=2048,D=64,Q=16,H=2,C=129,C8=16,K=8192.
// Round 24: attn frozen at r20 EXACT (317.6us best; r18/r21/r22/r23 all
// regressed -> 2-way split is the bracket optimum). New lever: the serial
// prologue. pack_adj (67MB BW sweep) is independent of repack/qkv but ran
// serially. Now: repack_all first (qkv's only dep), then ONE merged dispatch
// prep_fused (2560 blocks: bid<2048 pack_adj body, else qkv body) so the
// BW-bound adj sweep co-schedules with the MFMA-bound QKV projection; one
// launch fewer. attn/gate unchanged from r20.

typedef _Float16 h2_t __attribute__((ext_vector_type(2)));
typedef _Float16 h8_t __attribute__((ext_vector_type(8)));
typedef float    f4_t __attribute__((ext_vector_type(4)));
#define MFMA16x32(a,b,c) __builtin_amdgcn_mfma_f32_16x16x32_f16(a,b,c,0,0,0)

// ---- workspace layout (byte offsets; total 17,536,000 <= proven 22,025,248) --
#define OB_QG    0          // fp16 [2][8192][16]   524288
#define OB_KG    524288     // fp16 [2][8192][16]   524288
#define OB_VT    1048576    // fp16 [2][144][8192]  4718592
#define OB_MASK  5767168    // u32  [4][2048][64]   2097152
#define OB_WALL  7864320    // fp16 swz             107520
#define OB_HACC  7971840    // f32  [2][8192][132]  8650752 (+ lsum contiguous)
#define OB_LSUM  16622592   // f32  [2][8192]       65536
#define OB_WTRU  16688128   // fp16 swz [69][8][64][8]  565248
#define OB_WTC   17253376   // fp16 swz [69][4][64][8]  282624

// ---------------- repack_all: Wall + WtRu + WtC (swizzled) -------------------
__global__ __launch_bounds__(256) void repack_all(
    const float* __restrict__ Wq, const float* __restrict__ bq,
    const float* __restrict__ Wk, const float* __restrict__ bk,
    const float* __restrict__ Wv, const float* __restrict__ bv,
    const float* __restrict__ Wr, const float* __restrict__ br,
    const float* __restrict__ Wu, const float* __restrict__ bu,
    const float* __restrict__ Wc, const float* __restrict__ bc,
    _Float16* __restrict__ Wall, _Float16* __restrict__ WtRu,
    _Float16* __restrict__ WtC) {
    int idx = blockIdx.x * 256 + threadIdx.x;   // 6720 + 35328 + 17664 = 59712
    if (idx < 6720) {
        int ct = idx / 320;
        int rem = idx % 320;
        int s = rem >> 6, lane = rem & 63;
        int n = ct * 16 + (lane & 15);
        int quad = lane >> 4;
        int h2 = (n >= 164) ? 1 : 0;
        int nn = n - h2 * 164;
        h8_t v;
        #pragma unroll
        for (int j = 0; j < 8; ++j) {
            int k = s * 32 + quad * 8 + j;
            float f = 0.f;
            if (n < 328) {
                if (nn < 16) {
                    if (k < 129)       f = Wq[(h2 * 129 + k) * 16 + nn];
                    else if (k == 129) f = bq[h2 * 16 + nn];
                } else if (nn < 32) {
                    int d = nn - 16;
                    if (k < 129)       f = Wk[(h2 * 129 + k) * 16 + d];
                    else if (k == 129) f = bk[h2 * 16 + d];
                } else {
                    int vc = nn - 32;
                    if (vc < 129) {
                        if (k < 129)       f = Wv[(h2 * 129 + k) * 129 + vc];
                        else if (k == 129) f = bv[h2 * 129 + vc];
                    }
                }
            }
            v[j] = (_Float16)f;
        }
        *(h8_t*)(Wall + (size_t)idx * 8) = v;
    } else if (idx < 6720 + 35328) {
        int i2 = idx - 6720;
        int s = i2 / 512;
        int rem = i2 % 512;
        int ct = rem >> 6, lane = rem & 63;
        int o = ct * 16 + (lane & 15);
        int quad = lane >> 4;
        const float* W = (o < 64) ? Wr : Wu;
        const float* bb = (o < 64) ? br : bu;
        int oc = o & 63;
        h8_t v;
        #pragma unroll
        for (int j = 0; j < 8; ++j) {
            int kk = s * 32 + quad * 8 + j;
            float f = 0.f;
            if (kk < 2176) {
                int q = kk / 136, c = kk % 136;
                if (c < 129) f = W[(q * 129 + c) * 64 + oc];
            } else if (kk < 2192) {
                f = bb[(kk - 2176) * 64 + oc];
            }
            v[j] = (_Float16)f;
        }
        *(h8_t*)(WtRu + (size_t)i2 * 8) = v;
    } else if (idx < 59712) {
        int i2 = idx - 6720 - 35328;
        int s = i2 / 256;
        int rem = i2 % 256;
        int ct = rem >> 6, lane = rem & 63;
        int o = ct * 16 + (lane & 15);
        int quad = lane >> 4;
        h8_t v;
        #pragma unroll
        for (int j = 0; j < 8; ++j) {
            int kk = s * 32 + quad * 8 + j;
            float f = 0.f;
            if (kk < 2176) {
                int q = kk / 136, c = kk % 136;
                if (c < 129) f = Wc[(q * 129 + c) * 64 + o];
            } else if (kk < 2192) {
                f = bc[(kk - 2176) * 64 + o];
            }
            v[j] = (_Float16)f;
        }
        *(h8_t*)(WtC + (size_t)i2 * 8) = v;
    }
}

// ---- prep_fused: blocks 0..2047 pack adj->bitmask; 2048..2559 qkv MFMA ------
__global__ __launch_bounds__(256) void prep_fused(
    const int* __restrict__ adj, unsigned* __restrict__ mask,
    const float* __restrict__ x, const float* __restrict__ h,
    const _Float16* __restrict__ Wall,
    _Float16* __restrict__ qg, _Float16* __restrict__ kg,
    _Float16* __restrict__ vT) {
    __shared__ _Float16 at[16 * 168];
    __shared__ _Float16 vls[264 * 16];   // [vcol][row] fp16
    int t = threadIdx.x;
    int bid = blockIdx.x;
    if (bid < 2048) {
        // ---- pack_adj body (BW-bound; co-schedules with qkv blocks) ----
        long tg = (long)bid * 256 + t;
        for (int it = 0; it < 32; ++it) {
            long i = tg + (long)it * 524288;
            int a = adj[i];
            unsigned long long bal = __ballot(a != 0);
            if ((t & 63) == 0)
                *(unsigned long long*)(mask + (i >> 5)) = bal;
        }
        return;
    }
    // ---- qkv body ----
    int row0 = (bid - 2048) * 16;
    for (int idx = t; idx < 16 * 160; idx += 256) {
        int r = idx / 160, c = idx % 160;
        int grow = row0 + r;
        float v = 0.f;
        if (c < 65)       v = x[grow * 65 + c];
        else if (c < 129) v = h[grow * 64 + (c - 65)];
        else if (c == 129) v = 1.0f;
        at[r * 168 + c] = (_Float16)v;
    }
    __syncthreads();
    int lane = t & 63, w = t >> 6;
    int l16 = lane & 15, quad = lane >> 4;
    for (int ct = w; ct < 21; ct += 4) {
        f4_t acc; acc[0]=0.f; acc[1]=0.f; acc[2]=0.f; acc[3]=0.f;
        int n = ct * 16 + l16;
        const _Float16* wp = Wall + ((size_t)ct * 320 + lane) * 8;
        #pragma unroll
        for (int s = 0; s < 5; ++s) {
            h8_t a = *(const h8_t*)(at + l16 * 168 + s * 32 + quad * 8);
            h8_t b = *(const h8_t*)(wp + (size_t)s * 512);
            acc = MFMA16x32(a, b, acc);
        }
        if (n < 328) {
            int h2 = (n >= 164) ? 1 : 0;
            int nn = n - h2 * 164;
            #pragma unroll
            for (int r = 0; r < 4; ++r) {
                int row = quad * 4 + r;
                _Float16 v = (_Float16)acc[r];
                if (nn < 16)      qg[(h2 * 8192 + row0 + row) * 16 + nn] = v;
                else if (nn < 32) kg[(h2 * 8192 + row0 + row) * 16 + (nn - 16)] = v;
                else              vls[(h2 * 132 + (nn - 32)) * 16 + row] = v;
            }
        }
    }
    __syncthreads();
    // flush v: 264 cols x 16 rows as 2 x 16B bursts per col
    for (int idx = t; idx < 528; idx += 256) {
        int col = idx >> 1, half = idx & 1;
        int h2 = (col >= 132) ? 1 : 0;
        int cc = col - h2 * 132;
        uint4 v = ((const uint4*)vls)[idx];
        *(uint4*)(vT + ((size_t)(h2 * 144 + cc)) * 8192 + row0 + half * 8) = v;
    }
}

// --- attention: atomic-free, column-split (2 blocks/CU), dbuf gll (r20) ------
__global__ __launch_bounds__(256) void attn_fused(
    const _Float16* __restrict__ qg, const _Float16* __restrict__ kg,
    const _Float16* __restrict__ vT, const unsigned* __restrict__ mask,
    float* __restrict__ hacc, float* __restrict__ lsum, int ntiles) {
    __shared__ _Float16 vsm[2 * 5120];   // dbuf; up to 10 chunks x 1KB per buf
    __shared__ _Float16 pT[4 * 16 * 88];
    int t = threadIdx.x;
    // 512 blocks: pid&7 = XCD = hb (slice L2-resident); j = pid>>3:
    // nt = j&31 (q-tile), cs = j>>5 (column split half).
    int pid = blockIdx.x + 64 * blockIdx.y;
    int hb = pid & 7, j = pid >> 3;
    int nt = j & 31, cs = j >> 5;
    int h2 = hb >> 2, b = hb & 3;
    int base = h2 * 8192 + b * 2048;
    int n0 = nt * 64;
    int nbase = cs ? 5 : 0;              // first nb owned by this block
    int jj0 = cs ? 10 : 0, jjN = cs ? 18 : 10;   // staged V chunk range
    int lane = t & 63, w = t >> 6;
    int l16 = lane & 15, q = lane >> 4;
    int qrow = n0 + w * 16 + l16;
    _Float16* pTw = pT + w * 16 * 88;
    h8_t zero8;
    #pragma unroll
    for (int i = 0; i < 8; ++i) zero8[i] = (_Float16)0.f;
    h8_t qf = zero8;
    if (q < 2) qf = *(const h8_t*)(qg + (base + qrow) * 16 + 8 * q);
    const unsigned* mrw = mask + (b * 2048 + qrow) * 64;
    f4_t acc[5];
    #pragma unroll
    for (int i = 0; i < 5; ++i) { acc[i][0]=0.f; acc[i][1]=0.f; acc[i][2]=0.f; acc[i][3]=0.f; }
    float l_run = 0.f;

    // gll staging: LOCAL chunk s = jj-jj0 covers local rows 8s..8s+7. Lane L
    // writes slot byte s*1024+16L; stored key-chunk (L&7)^(L>>3) = involution
    // with read-side XOR on (local_row&7). cs offsets are multiples of 8 so
    // the involution is unchanged.
    int vcol_l = (lane >> 3);
    int kch_l  = (lane & 7) ^ vcol_l;
    const _Float16* vtb = vT + (size_t)h2 * 144 * 8192 + b * 2048 + 8 * kch_l;

    h8_t kpre[4];
    uint2 mpre;
    // prologue: DMA tile 0 -> buf 0; K/mask prefetch tile 0
    for (int jj = jj0 + w; jj < jjN; jj += 4)
        __builtin_amdgcn_global_load_lds(
            (const void*)(vtb + (size_t)(8 * jj + vcol_l) * 8192),
            (void*)(vsm + (jj - jj0) * 512), 16, 0, 0);
    #pragma unroll
    for (int ct = 0; ct < 4; ++ct) {
        kpre[ct] = zero8;
        if (q < 2)
            kpre[ct] = *(const h8_t*)(kg + (base + 16 * ct + l16) * 16 + 8 * q);
    }
    mpre = *(const uint2*)mrw;

    for (int mt = 0; mt < ntiles; ++mt) {
        int cur = mt & 1;
        // ---- QK + softmax (V DMA(mt) into buf cur in flight underneath) ----
        h8_t kf[4];
        #pragma unroll
        for (int ct = 0; ct < 4; ++ct) kf[ct] = kpre[ct];
        uint2 mw = mpre;
        f4_t st[4];
        #pragma unroll
        for (int ct = 0; ct < 4; ++ct) {
            f4_t z4; z4[0]=0.f; z4[1]=0.f; z4[2]=0.f; z4[3]=0.f;
            st[ct] = MFMA16x32(kf[ct], qf, z4);
        }
        #pragma unroll
        for (int ct = 0; ct < 4; ++ct) {
            unsigned wb = (ct < 2) ? mw.x : mw.y;
            float p[4];
            #pragma unroll
            for (int r = 0; r < 4; ++r) {
                float sc = st[ct][r] * 0.25f;
                sc = sc > 0.f ? sc : 0.2f * sc;
                int bit = ((ct & 1) ? 16 : 0) + 4 * q + r;
                p[r] = ((wb >> bit) & 1u) ? __expf(sc) : 0.f;
                l_run += p[r];
            }
            h2_t p01; p01[0] = (_Float16)p[0]; p01[1] = (_Float16)p[1];
            h2_t p23; p23[0] = (_Float16)p[2]; p23[1] = (_Float16)p[3];
            *(h2_t*)(pTw + l16 * 88 + 16 * ct + 4 * q)     = p01;
            *(h2_t*)(pTw + l16 * 88 + 16 * ct + 4 * q + 2) = p23;
        }
        // prefetch next tile's K/mask (consumed next iteration)
        if (mt + 1 < ntiles) {
            int m1 = (mt + 1) * 64;
            #pragma unroll
            for (int ct = 0; ct < 4; ++ct) {
                kpre[ct] = zero8;
                if (q < 2)
                    kpre[ct] = *(const h8_t*)(kg + (base + m1 + 16 * ct + l16) * 16 + 8 * q);
            }
            mpre = *(const uint2*)(mrw + (m1 >> 5));
        }
        // ONE barrier: per-wave vmcnt(0) drain completes DMA(mt); also all
        // waves finished PV(mt-1) on buf cur^1 -> safe to DMA into it.
        __syncthreads();
        if (mt + 1 < ntiles) {
            int m1 = (mt + 1) * 64;
            for (int jj = jj0 + w; jj < jjN; jj += 4)
                __builtin_amdgcn_global_load_lds(
                    (const void*)(vtb + (size_t)(8 * jj + vcol_l) * 8192 + m1),
                    (void*)(vsm + (cur ^ 1) * 5120 + (jj - jj0) * 512), 16, 0, 0);
        }
        // ---- PV on buf cur (swizzled reads; local rows 16i+l16) ----
        // cs=1 runs a 5th dummy nb into unwritten LDS; its store is guarded.
        const char* vbb = (const char*)(vsm + cur * 5120);
        __builtin_amdgcn_s_setprio(1);
        #pragma unroll
        for (int kh = 0; kh < 2; ++kh) {
            h8_t ap = *(const h8_t*)(pTw + l16 * 88 + 32 * kh + 8 * q);
            int xsw = (((kh << 2) + q) ^ (l16 & 7)) << 4;
            #pragma unroll
            for (int i = 0; i < 5; ++i) {
                h8_t vf = *(const h8_t*)(vbb + ((16 * i + l16) << 7) + xsw);
                acc[i] = MFMA16x32(ap, vf, acc[i]);
            }
        }
        __builtin_amdgcn_s_setprio(0);
    }
    l_run += __shfl_xor(l_run, 16);
    l_run += __shfl_xor(l_run, 32);
    float* hc = hacc + (size_t)h2 * 8192 * 132;
    if (cs == 0 && q == 0)
        lsum[h2 * 8192 + b * 2048 + n0 + w * 16 + l16] = l_run;
    #pragma unroll
    for (int i = 0; i < 5; ++i) {
        int vc = 16 * (nbase + i) + l16;
        if (vc < 132) {
            #pragma unroll
            for (int r = 0; r < 4; ++r) {
                int grow = b * 2048 + n0 + w * 16 + 4 * q + r;
                hc[grow * 132 + vc] = acc[i][r];
            }
        }
    }
}

// ---------------- fused gates: GEMM1 (r,u) -> LDS -> GEMM2 (c) -> out --------
__global__ __launch_bounds__(256) void gate_fused(
    const float* __restrict__ hacc, const float* __restrict__ lsum,
    const int* __restrict__ nodes, const float* __restrict__ qv,
    const _Float16* __restrict__ WtRu, const _Float16* __restrict__ WtC,
    const float* __restrict__ hbuf, const float* __restrict__ x,
    float* __restrict__ out) {
    __shared__ _Float16 selh[16 * 152];
    __shared__ _Float16 selh2[16 * 152];
    __shared__ float qvs[16 * 17];
    __shared__ float invl[32];
    __shared__ float hslds[16 * 66];
    __shared__ float ulds[16 * 66];
    int t = threadIdx.x;
    int k0 = blockIdx.x * 16;
    if (t < 32) {
        int r = t >> 1, hh = t & 1;
        int grow = nodes[k0 + r];
        invl[t] = 0.5f / lsum[hh * 8192 + grow];
    }
    __syncthreads();
    // stage selh (normalized head-mean) + selh2 x-part + qvs
    for (int idx = t; idx < 16 * 136; idx += 256) {
        int r = idx / 136, c = idx % 136;
        _Float16 v = (_Float16)0.f;
        if (c < 132) {
            int grow = nodes[k0 + r];
            v = (_Float16)(hacc[grow * 132 + c] * invl[r * 2] +
                           hacc[8192 * 132 + grow * 132 + c] * invl[r * 2 + 1]);
        }
        selh[r * 152 + c] = v;
    }
    for (int idx = t; idx < 16 * 136; idx += 256) {
        int r = idx / 136, c = idx % 136;
        _Float16 v = (_Float16)0.f;
        if (c < 65) v = (_Float16)x[nodes[k0 + r] * 65 + c];
        selh2[r * 152 + c] = v;     // cols 65..135 filled/zeroed after GEMM1
    }
    if (t < 256) {
        int r = t >> 4, q = t & 15;
        qvs[r * 17 + q] = qv[(k0 + r) * 16 + q];
    }
    __syncthreads();
    int lane = t & 63, w = t >> 6;
    int l16 = lane & 15, quad = lane >> 4;
    // ---- GEMM1: r,u (128 cols; wave w owns ct 2w, 2w+1) ----
    f4_t acc0, acc1;
    acc0[0]=0.f;acc0[1]=0.f;acc0[2]=0.f;acc0[3]=0.f;
    acc1[0]=0.f;acc1[1]=0.f;acc1[2]=0.f;acc1[3]=0.f;
    const _Float16* wp0 = WtRu + ((size_t)(2 * w) * 64 + lane) * 8;
    const _Float16* wp1 = wp0 + 512;
    for (int step = 0; step < 69; ++step) {
        h8_t a;
        if (step < 68) {
            int chunk = 4 * step + quad;
            int q = chunk / 17;
            int c0 = (chunk - q * 17) * 8;
            h8_t s8 = *(const h8_t*)(selh + l16 * 152 + c0);
            _Float16 qh = (_Float16)qvs[l16 * 17 + q];
            #pragma unroll
            for (int j = 0; j < 8; ++j) a[j] = s8[j] * qh;
        } else {
            int kl = quad * 8;
            #pragma unroll
            for (int j = 0; j < 8; ++j) {
                int kq = kl + j;
                a[j] = (kq < 16) ? (_Float16)qvs[l16 * 17 + kq] : (_Float16)0.f;
            }
        }
        h8_t b0 = *(const h8_t*)(wp0 + (size_t)step * 4096);
        h8_t b1 = *(const h8_t*)(wp1 + (size_t)step * 4096);
        acc0 = MFMA16x32(a, b0, acc0);
        acc1 = MFMA16x32(a, b1, acc1);
    }
    // epilogue GEMM1 -> LDS (hsel f32 + fp16 into selh2, u f32)
    #pragma unroll
    for (int tt = 0; tt < 2; ++tt) {
        f4_t ac = tt ? acc1 : acc0;
        int o = (2 * w + tt) * 16 + l16;
        #pragma unroll
        for (int r = 0; r < 4; ++r) {
            int row = quad * 4 + r;
            float sg = 1.f / (1.f + __expf(-ac[r]));
            if (o < 64) {
                float hs = sg * hbuf[nodes[k0 + row] * 64 + o];
                hslds[row * 66 + o] = hs;
                selh2[row * 152 + 65 + o] = (_Float16)hs;
            } else {
                ulds[row * 66 + (o - 64)] = sg;
            }
        }
    }
    // zero selh2 cols 129..135 (read by last A-chunk)
    if (t < 112) {
        int r = t / 7, c = 129 + (t % 7);
        selh2[r * 152 + c] = (_Float16)0.f;
    }
    __syncthreads();
    // ---- GEMM2: c (64 cols; wave w owns ct w) ----
    f4_t acc2;
    acc2[0]=0.f;acc2[1]=0.f;acc2[2]=0.f;acc2[3]=0.f;
    const _Float16* wp = WtC + ((size_t)w * 64 + lane) * 8;
    for (int step = 0; step < 69; ++step) {
        h8_t a;
        if (step < 68) {
            int chunk = 4 * step + quad;
            int q = chunk / 17;
            int c0 = (chunk - q * 17) * 8;
            h8_t s8 = *(const h8_t*)(selh2 + l16 * 152 + c0);
            _Float16 qh = (_Float16)qvs[l16 * 17 + q];
            #pragma unroll
            for (int j = 0; j < 8; ++j) a[j] = s8[j] * qh;
        } else {
            int kl = quad * 8;
            #pragma unroll
            for (int j = 0; j < 8; ++j) {
                int kq = kl + j;
                a[j] = (kq < 16) ? (_Float16)qvs[l16 * 17 + kq] : (_Float16)0.f;
            }
        }
        h8_t b = *(const h8_t*)(wp + (size_t)step * 2048);
        acc2 = MFMA16x32(a, b, acc2);
    }
    int o = w * 16 + l16;
    #pragma unroll
    for (int r = 0; r < 4; ++r) {
        int row = quad * 4 + r;
        float cv = tanhf(acc2[r]);
        float hs = hslds[row * 66 + o];
        float uv = ulds[row * 66 + o];
        out[(k0 + row) * 64 + o] = (1.f - uv) * hs + uv * cv;
    }
}

extern "C" void kernel_launch(void* const* d_in, const int* in_sizes, int n_in,
                              void* d_out, int out_size, void* d_ws, size_t ws_size,
                              hipStream_t stream) {
    const float* x   = (const float*)d_in[0];
    const float* h   = (const float*)d_in[1];
    const float* qv  = (const float*)d_in[2];
    const int*   adj = (const int*)d_in[3];
    const int*   nod = (const int*)d_in[4];
    const float* Wq  = (const float*)d_in[5];
    const float* bq  = (const float*)d_in[6];
    const float* Wk  = (const float*)d_in[7];
    const float* bk  = (const float*)d_in[8];
    const float* Wv  = (const float*)d_in[9];
    const float* bv  = (const float*)d_in[10];
    const float* Wr  = (const float*)d_in[11];
    const float* br  = (const float*)d_in[12];
    const float* Wu  = (const float*)d_in[13];
    const float* bu  = (const float*)d_in[14];
    const float* Wc  = (const float*)d_in[15];
    const float* bc  = (const float*)d_in[16];

    char* wsb = (char*)d_ws;
    _Float16* qg   = (_Float16*)(wsb + OB_QG);
    _Float16* kg   = (_Float16*)(wsb + OB_KG);
    _Float16* vT   = (_Float16*)(wsb + OB_VT);
    unsigned* mask = (unsigned*)(wsb + OB_MASK);
    _Float16* Wall = (_Float16*)(wsb + OB_WALL);
    float* hacc    = (float*)(wsb + OB_HACC);
    float* lsum    = (float*)(wsb + OB_LSUM);
    _Float16* WtRu = (_Float16*)(wsb + OB_WTRU);
    _Float16* WtC  = (_Float16*)(wsb + OB_WTC);

    repack_all<<<dim3(234), 256, 0, stream>>>(Wq, bq, Wk, bk, Wv, bv,
                                              Wr, br, Wu, bu, Wc, bc,
                                              Wall, WtRu, WtC);
    prep_fused<<<dim3(2560), 256, 0, stream>>>(adj, mask, x, h, Wall,
                                               qg, kg, vT);
    attn_fused<<<dim3(64, 8, 1), 256, 0, stream>>>(qg, kg, vT, mask,
                                                   hacc, lsum, 32);
    gate_fused<<<dim3(512), 256, 0, stream>>>(hacc, lsum, nod, qv,
                                              WtRu, WtC, h, x,
                                              (float*)d_out);
}